// Round 3
// baseline (485.274 us; speedup 1.0000x reference)
//
#include <hip/hip_runtime.h>

// AttentionSubsample (LeViT) — round 3.
// Round-2 diagnosis: kv_gemm store-scatter bound (64x 2B-scattered vT writes
// per wave-store). Fix: compute v-columns in transposed MFMA orientation
// (mfma(W,x) instead of mfma(x,W)) so tokens land in lanes -> coalesced
// 32B-segment stores. proj gets an N-split x3 for occupancy.

#define Bn   512
#define Nn   196
#define NQn  49
#define Cn   256
#define Hn   8

typedef float    float4v __attribute__((ext_vector_type(4)));
typedef _Float16 half8v  __attribute__((ext_vector_type(8)));
typedef _Float16 half4v  __attribute__((ext_vector_type(4)));

// ---------------------------------------------------------------- prep ----
__global__ __launch_bounds__(256) void prep_kernel(
    const float* __restrict__ Wkv, const float* __restrict__ Wq,
    const float* __restrict__ Wp,
    const float* __restrict__ g_kv, const float* __restrict__ b_kv,
    const float* __restrict__ m_kv, const float* __restrict__ v_kv,
    const float* __restrict__ g_q,  const float* __restrict__ b_q,
    const float* __restrict__ m_q,  const float* __restrict__ v_q,
    const float* __restrict__ g_p,  const float* __restrict__ b_p,
    const float* __restrict__ m_p,  const float* __restrict__ v_p,
    const float* __restrict__ ab,   const int* __restrict__ idxs,
    _Float16* __restrict__ Whkv, _Float16* __restrict__ Whq,
    _Float16* __restrict__ Whp,
    float* __restrict__ kv_s, float* __restrict__ kv_sh,
    float* __restrict__ q_s,  float* __restrict__ q_sh,
    float* __restrict__ p_s,  float* __restrict__ p_sh,
    float* __restrict__ biasT)
{
  int i = blockIdx.x * 256 + threadIdx.x;
  if (i < 98304) { Whkv[i] = (_Float16)Wkv[i]; return; }
  i -= 98304;
  if (i < 32768) { Whq[i] = (_Float16)Wq[i]; return; }
  i -= 32768;
  if (i < 98304) { Whp[i] = (_Float16)Wp[i]; return; }
  i -= 98304;
  if (i < 896) {
    if (i < 384) {
      float s = g_kv[i] * rsqrtf(v_kv[i] + 1e-5f);
      kv_s[i] = s; kv_sh[i] = b_kv[i] - m_kv[i] * s;
    } else if (i < 512) {
      int j = i - 384;
      float s = g_q[j] * rsqrtf(v_q[j] + 1e-5f);
      q_s[j] = 0.25f * s; q_sh[j] = 0.25f * (b_q[j] - m_q[j] * s);
    } else {
      int j = i - 512;
      float s = g_p[j] * rsqrtf(v_p[j] + 1e-5f);
      p_s[j] = s; p_sh[j] = b_p[j] - m_p[j] * s;
    }
    return;
  }
  i -= 896;
  if (i < Hn * NQn * Nn) {                       // biasT[h][n][64] = ab[h, idxs[q,n]]
    unsigned h = (unsigned)i / (NQn * Nn);
    unsigned rem = (unsigned)i - h * (NQn * Nn);
    unsigned q = rem / Nn, n = rem - q * Nn;
    biasT[((size_t)h * 208 + n) * 64 + q] = ab[h * Nn + idxs[q * Nn + n]];
  }
}

// ------------------------------------------------------------- kv gemm ----
// grid 1568: 64 token-rows x all 384 cols. Two MFMA orientations:
//   k-cols:  mfma(x, W) -> D[token][c], store kk[n][c] (16-lane 32B runs)
//   v-cols:  mfma(W, x) -> D[c][token], store vT[vd][n] (16-lane 32B runs)
// Same x fragments feed both (A/B frag layouts are symmetric).
__global__ __launch_bounds__(256, 4) void kv_gemm_kernel(
    const float* __restrict__ x, const _Float16* __restrict__ Whkv,
    const float* __restrict__ kv_s, const float* __restrict__ kv_sh,
    _Float16* __restrict__ kk, _Float16* __restrict__ vT)
{
  const int tid = threadIdx.x, lane = tid & 63, wid = tid >> 6;
  const int row_in = lane & 15, kgrp = lane >> 4;
  const unsigned g_a = blockIdx.x * 64 + wid * 16 + row_in;

  half8v af[8];
  const float* xrow = x + (size_t)g_a * Cn + kgrp * 8;
#pragma unroll
  for (int kc = 0; kc < 8; ++kc) {
    float4v a0 = *reinterpret_cast<const float4v*>(xrow + kc * 32);
    float4v a1 = *reinterpret_cast<const float4v*>(xrow + kc * 32 + 4);
    half8v t;
    t[0]=(_Float16)a0[0]; t[1]=(_Float16)a0[1]; t[2]=(_Float16)a0[2]; t[3]=(_Float16)a0[3];
    t[4]=(_Float16)a1[0]; t[5]=(_Float16)a1[1]; t[6]=(_Float16)a1[2]; t[7]=(_Float16)a1[3];
    af[kc] = t;
  }
  // lane-row (b,n): used for v-stores (tokens in lanes)
  const unsigned bl = g_a / 196u, nl = g_a - bl * 196u;
  // kgrp-rows (b,n): used for k-stores (tokens in acc rows)
  unsigned bk_[4], nk_[4];
#pragma unroll
  for (int i = 0; i < 4; ++i) {
    unsigned g = blockIdx.x * 64 + wid * 16 + kgrp * 4 + i;
    unsigned b = g / 196u;
    bk_[i] = b; nk_[i] = g - b * 196u;
  }

#pragma unroll
  for (int h = 0; h < 8; ++h) {
    { // ---- k columns: nt = 3h, c = row_in (0..15) ----
      const _Float16* wrow = Whkv + (size_t)((3 * h) * 16 + row_in) * Cn + kgrp * 8;
      float4v acc = (float4v){0.f, 0.f, 0.f, 0.f};
#pragma unroll
      for (int kc = 0; kc < 8; ++kc) {
        half8v wf = *reinterpret_cast<const half8v*>(wrow + kc * 32);
        acc = __builtin_amdgcn_mfma_f32_16x16x32_f16(af[kc], wf, acc, 0, 0, 0);
      }
      int j = 48 * h + row_in;
      float s = kv_s[j], sh = kv_sh[j];
#pragma unroll
      for (int i = 0; i < 4; ++i) {
        float y = acc[i] * s + sh;
        kk[(((size_t)bk_[i] * 8 + h) * 208 + nk_[i]) * 16 + row_in] = (_Float16)y;
      }
    }
#pragma unroll
    for (int m3 = 1; m3 < 3; ++m3) {  // ---- v columns (transposed orient) ----
      const int nt = 3 * h + m3;
      const _Float16* wrow = Whkv + (size_t)(nt * 16 + row_in) * Cn + kgrp * 8;
      float4v acc = (float4v){0.f, 0.f, 0.f, 0.f};
#pragma unroll
      for (int kc = 0; kc < 8; ++kc) {
        half8v wf = *reinterpret_cast<const half8v*>(wrow + kc * 32);
        acc = __builtin_amdgcn_mfma_f32_16x16x32_f16(wf, af[kc], acc, 0, 0, 0);
      }
#pragma unroll
      for (int i = 0; i < 4; ++i) {
        int j = nt * 16 + kgrp * 4 + i;          // W row = kv channel
        float y = acc[i] * kv_s[j] + kv_sh[j];
        int vd = (m3 - 1) * 16 + kgrp * 4 + i;   // 0..31
        vT[(((size_t)bl * 8 + h) * 32 + vd) * 208 + nl] = (_Float16)y;
      }
    }
  }
}

// -------------------------------------------------------------- q gemm ----
// grid 392: 64 q-rows x 128 cols. Writes qh[bh][64][16], rows>=49 garbage-ok.
__global__ __launch_bounds__(256, 6) void q_gemm_kernel(
    const float* __restrict__ x, const _Float16* __restrict__ Whq,
    const float* __restrict__ q_s, const float* __restrict__ q_sh,
    _Float16* __restrict__ qh)
{
  const int tid = threadIdx.x, lane = tid & 63, wid = tid >> 6;
  const int row_in = lane & 15, kgrp = lane >> 4;

  unsigned g = blockIdx.x * 64 + wid * 16 + row_in;      // 0..25087
  unsigned b = g / 49u, qq = g - b * 49u;
  unsigned qi = qq / 7u, qj = qq - qi * 7u;
  unsigned n = 28u * qi + 2u * qj;
  const float* xrow = x + ((size_t)b * Nn + n) * Cn + kgrp * 8;

  half8v af[8];
#pragma unroll
  for (int kc = 0; kc < 8; ++kc) {
    float4v a0 = *reinterpret_cast<const float4v*>(xrow + kc * 32);
    float4v a1 = *reinterpret_cast<const float4v*>(xrow + kc * 32 + 4);
    half8v t;
    t[0]=(_Float16)a0[0]; t[1]=(_Float16)a0[1]; t[2]=(_Float16)a0[2]; t[3]=(_Float16)a0[3];
    t[4]=(_Float16)a1[0]; t[5]=(_Float16)a1[1]; t[6]=(_Float16)a1[2]; t[7]=(_Float16)a1[3];
    af[kc] = t;
  }
  unsigned b2_[4], q2_[4];
#pragma unroll
  for (int i = 0; i < 4; ++i) {
    unsigned gg = blockIdx.x * 64 + wid * 16 + kgrp * 4 + i;
    unsigned bb = gg / 49u;
    b2_[i] = bb; q2_[i] = gg - bb * 49u;
  }
#pragma unroll
  for (int nt = 0; nt < 8; ++nt) {
    float4v acc = (float4v){0.f, 0.f, 0.f, 0.f};
    const _Float16* wrow = Whq + (size_t)(nt * 16 + row_in) * Cn + kgrp * 8;
#pragma unroll
    for (int kc = 0; kc < 8; ++kc) {
      half8v bf = *reinterpret_cast<const half8v*>(wrow + kc * 32);
      acc = __builtin_amdgcn_mfma_f32_16x16x32_f16(af[kc], bf, acc, 0, 0, 0);
    }
    int j = nt * 16 + row_in;                    // 0..127
    float s = q_s[j], sh = q_sh[j];
    int h = j >> 4, c = j & 15;
#pragma unroll
    for (int i = 0; i < 4; ++i) {
      float y = acc[i] * s + sh;
      qh[(((size_t)b2_[i] * 8 + h) * 64 + q2_[i]) * 16 + c] = (_Float16)y;
    }
  }
}

// ---------------------------------------------------------------- attn ----
// grid 4096 (b*8+h). 4 waves, wave w owns q-tile rows w*16..w*16+15.
// Register softmax; only LDS is the per-wave P buffer. No barriers.
__global__ __launch_bounds__(256, 4) void attn_kernel(
    const _Float16* __restrict__ kk, const _Float16* __restrict__ vT,
    const _Float16* __restrict__ qh, const float* __restrict__ biasT,
    _Float16* __restrict__ oh)
{
  const int bh = blockIdx.x;
  const int b = bh >> 3, h = bh & 7;
  const int tid = threadIdx.x, lane = tid & 63, wid = tid >> 6;
  const int row_in = lane & 15, kgrp = lane >> 4;

  __shared__ _Float16 sP[4][16][212];

  // ---- QK^T + bias, logits in registers -------------------------------
  half4v aq = *reinterpret_cast<const half4v*>(
      qh + ((size_t)bh * 64 + wid * 16 + row_in) * 16 + kgrp * 4);
  const _Float16* kbase = kk + (size_t)bh * 208 * 16;
  const float* bbase = biasT + ((size_t)h * 208) * 64 + wid * 16 + kgrp * 4;

  float4v acc[13];
#pragma unroll
  for (int nt = 0; nt < 13; ++nt) {
    half4v bk = *reinterpret_cast<const half4v*>(kbase + (nt * 16 + row_in) * 16 + kgrp * 4);
    float4v a = (float4v){0.f, 0.f, 0.f, 0.f};
    a = __builtin_amdgcn_mfma_f32_16x16x16f16(aq, bk, a, 0, 0, 0);
    float4v bias = *reinterpret_cast<const float4v*>(bbase + (size_t)(nt * 16 + row_in) * 64);
    acc[nt] = a + bias;
  }

  // ---- register softmax: row q lives in 16-lane group (kgrp*4+i) -------
  const bool tail_ok = (row_in < 4);             // nt=12 -> n=192+row_in valid iff <196
  float mx[4], sm[4];
#pragma unroll
  for (int i = 0; i < 4; ++i) mx[i] = -1e30f;
#pragma unroll
  for (int nt = 0; nt < 13; ++nt) {
    bool valid = (nt < 12) | tail_ok;
#pragma unroll
    for (int i = 0; i < 4; ++i)
      mx[i] = fmaxf(mx[i], valid ? acc[nt][i] : -1e30f);
  }
#pragma unroll
  for (int i = 0; i < 4; ++i) {
#pragma unroll
    for (int off = 8; off >= 1; off >>= 1)
      mx[i] = fmaxf(mx[i], __shfl_xor(mx[i], off, 64));
  }
#pragma unroll
  for (int i = 0; i < 4; ++i) sm[i] = 0.f;
#pragma unroll
  for (int nt = 0; nt < 13; ++nt) {
    bool valid = (nt < 12) | tail_ok;
#pragma unroll
    for (int i = 0; i < 4; ++i) {
      float e = valid ? __expf(acc[nt][i] - mx[i]) : 0.f;
      acc[nt][i] = e; sm[i] += e;
    }
  }
#pragma unroll
  for (int i = 0; i < 4; ++i) {
#pragma unroll
    for (int off = 8; off >= 1; off >>= 1)
      sm[i] += __shfl_xor(sm[i], off, 64);
  }
  float inv[4];
#pragma unroll
  for (int i = 0; i < 4; ++i) inv[i] = 1.f / sm[i];

  // ---- P -> per-wave LDS (layout change for PV A-operand) --------------
#pragma unroll
  for (int nt = 0; nt < 13; ++nt)
#pragma unroll
    for (int i = 0; i < 4; ++i)
      sP[wid][kgrp * 4 + i][nt * 16 + row_in] = (_Float16)(acc[nt][i] * inv[i]);

  // ---- O = P @ V (vT frags straight from global), hardswish, store -----
  const _Float16* vbase = vT + (size_t)bh * 32 * 208 + kgrp * 4;
  float4v o0 = (float4v){0.f, 0.f, 0.f, 0.f};
  float4v o1 = (float4v){0.f, 0.f, 0.f, 0.f};
#pragma unroll
  for (int kc = 0; kc < 13; ++kc) {
    half4v ap = *reinterpret_cast<const half4v*>(&sP[wid][row_in][kc * 16 + kgrp * 4]);
    half4v bv0 = *reinterpret_cast<const half4v*>(vbase + (size_t)row_in * 208 + kc * 16);
    half4v bv1 = *reinterpret_cast<const half4v*>(vbase + (size_t)(16 + row_in) * 208 + kc * 16);
    o0 = __builtin_amdgcn_mfma_f32_16x16x16f16(ap, bv0, o0, 0, 0, 0);
    o1 = __builtin_amdgcn_mfma_f32_16x16x16f16(ap, bv1, o1, 0, 0, 0);
  }
#pragma unroll
  for (int i = 0; i < 4; ++i) {
    int q = wid * 16 + kgrp * 4 + i;
    if (q < NQn) {
      size_t base = ((size_t)b * NQn + q) * 256 + h * 32 + row_in;
      float v0 = o0[i], v1 = o1[i];
      float hs0 = v0 * fminf(fmaxf(v0 + 3.f, 0.f), 6.f) * (1.f / 6.f);
      float hs1 = v1 * fminf(fmaxf(v1 + 3.f, 0.f), 6.f) * (1.f / 6.f);
      oh[base]      = (_Float16)hs0;
      oh[base + 16] = (_Float16)hs1;
    }
  }
}

// ---------------------------------------------------------------- proj ----
// grid (392, 3): 64 rows x 128 cols per block; A (f16) in regs, W f16 from L2.
__global__ __launch_bounds__(256, 6) void proj_kernel(
    const _Float16* __restrict__ oh, const _Float16* __restrict__ Whp,
    const float* __restrict__ p_s, const float* __restrict__ p_sh,
    float* __restrict__ out)
{
  const int tid = threadIdx.x, lane = tid & 63, wid = tid >> 6;
  const int row_in = lane & 15, kgrp = lane >> 4;
  const size_t g_a = (size_t)blockIdx.x * 64 + wid * 16 + row_in;
  const int j0 = blockIdx.y * 128;

  half8v af[8];
  const _Float16* arow = oh + g_a * 256 + kgrp * 8;
#pragma unroll
  for (int kc = 0; kc < 8; ++kc)
    af[kc] = *reinterpret_cast<const half8v*>(arow + kc * 32);

  const size_t r0 = (size_t)blockIdx.x * 64 + wid * 16 + kgrp * 4;
#pragma unroll
  for (int nt = 0; nt < 8; ++nt) {
    float4v acc = (float4v){0.f, 0.f, 0.f, 0.f};
    const _Float16* wrow = Whp + (size_t)(j0 + nt * 16 + row_in) * Cn + kgrp * 8;
#pragma unroll
    for (int kc = 0; kc < 8; ++kc) {
      half8v bf = *reinterpret_cast<const half8v*>(wrow + kc * 32);
      acc = __builtin_amdgcn_mfma_f32_16x16x32_f16(af[kc], bf, acc, 0, 0, 0);
    }
    int j = j0 + nt * 16 + row_in;
    float s = p_s[j], sh = p_sh[j];
#pragma unroll
    for (int i = 0; i < 4; ++i)
      out[(r0 + i) * 384 + j] = acc[i] * s + sh;
  }
}

// -------------------------------------------------------------- launch ----
extern "C" void kernel_launch(void* const* d_in, const int* in_sizes, int n_in,
                              void* d_out, int out_size, void* d_ws, size_t ws_size,
                              hipStream_t stream) {
  const float* x    = (const float*)d_in[0];
  const float* Wkv  = (const float*)d_in[1];
  const float* g_kv = (const float*)d_in[2];
  const float* b_kv = (const float*)d_in[3];
  const float* m_kv = (const float*)d_in[4];
  const float* v_kv = (const float*)d_in[5];
  const float* Wq   = (const float*)d_in[6];
  const float* g_q  = (const float*)d_in[7];
  const float* b_q  = (const float*)d_in[8];
  const float* m_q  = (const float*)d_in[9];
  const float* v_q  = (const float*)d_in[10];
  const float* Wp   = (const float*)d_in[11];
  const float* g_p  = (const float*)d_in[12];
  const float* b_p  = (const float*)d_in[13];
  const float* m_p  = (const float*)d_in[14];
  const float* v_p  = (const float*)d_in[15];
  const float* ab   = (const float*)d_in[16];
  const int*   idxs = (const int*)d_in[17];
  float* out = (float*)d_out;

  // workspace carve (~104 MB)
  char* w = (char*)d_ws;
  _Float16* oh    = (_Float16*)(w);                     // 25088*256*2   = 12,845,056
  _Float16* kk    = (_Float16*)(w + 12845056);          // 4096*208*16*2 = 27,262,976
  _Float16* vT    = (_Float16*)(w + 40108032);          // 4096*32*208*2 = 54,525,952
  _Float16* qh    = (_Float16*)(w + 94633984);          // 4096*64*16*2  =  8,388,608
  _Float16* Whkv  = (_Float16*)(w + 103022592);         // 384*256*2     =    196,608
  _Float16* Whq   = (_Float16*)(w + 103219200);         // 128*256*2     =     65,536
  _Float16* Whp   = (_Float16*)(w + 103284736);         // 384*256*2     =    196,608
  float*    biasT = (float*)   (w + 103481344);         // 8*208*64*4    =    425,984
  float*    kv_s  = (float*)   (w + 103907328);
  float*    kv_sh = (float*)   (w + 103908864);
  float*    q_s   = (float*)   (w + 103910400);
  float*    q_sh  = (float*)   (w + 103910912);
  float*    p_s   = (float*)   (w + 103911424);
  float*    p_sh  = (float*)   (w + 103912960);

  prep_kernel<<<1200, 256, 0, stream>>>(Wkv, Wq, Wp,
                                        g_kv, b_kv, m_kv, v_kv,
                                        g_q, b_q, m_q, v_q,
                                        g_p, b_p, m_p, v_p,
                                        ab, idxs,
                                        Whkv, Whq, Whp,
                                        kv_s, kv_sh, q_s, q_sh, p_s, p_sh, biasT);
  kv_gemm_kernel<<<1568, 256, 0, stream>>>(x, Whkv, kv_s, kv_sh, kk, vT);
  q_gemm_kernel<<<392, 256, 0, stream>>>(x, Whq, q_s, q_sh, qh);
  attn_kernel<<<Bn * Hn, 256, 0, stream>>>(kk, vT, qh, biasT, oh);
  proj_kernel<<<dim3(392, 3), 256, 0, stream>>>(oh, Whp, p_s, p_sh, out);
}

// Round 4
// 292.872 us; speedup vs baseline: 1.6569x; 1.6569x over previous
//
#include <hip/hip_runtime.h>

// AttentionSubsample (LeViT) — round 4.
// Round-3 diagnosis: L2 request-rate bound — every W/k/v fragment load was a
// 16-segment gather. Fix: pre-pack ALL MFMA operands in fragment order
// ([tile][kc][lane]) so every wave load/store in the hot kernels is a single
// contiguous 512B-1KB run. kv_gemm stages its x-tile once per block into LDS
// (frag order), holds W fragments in registers, and emits k/v/q already
// fragment-packed for attn.

#define Bn   512
#define Nn   196
#define NQn  49
#define Cn   256
#define Hn   8

typedef float    float4v __attribute__((ext_vector_type(4)));
typedef _Float16 half8v  __attribute__((ext_vector_type(8)));
typedef _Float16 half4v  __attribute__((ext_vector_type(4)));

// ---------------------------------------------------------------- prep ----
// Packs weights/bias into fragment order; folds BN params.
//   WF[tile][kc][lane]  (16B/lane):  W[tile*16 + (lane&15)][kc*32 + (lane>>4)*8 .. +8]
//   biasF[h][qt][nt][lane] (float4): ab[h, idxs[qt*16+(lane>>4)*4+i, nt*16+(lane&15)]]
__global__ __launch_bounds__(256) void prep_kernel(
    const float* __restrict__ Wkv, const float* __restrict__ Wq,
    const float* __restrict__ Wp,
    const float* __restrict__ g_kv, const float* __restrict__ b_kv,
    const float* __restrict__ m_kv, const float* __restrict__ v_kv,
    const float* __restrict__ g_q,  const float* __restrict__ b_q,
    const float* __restrict__ m_q,  const float* __restrict__ v_q,
    const float* __restrict__ g_p,  const float* __restrict__ b_p,
    const float* __restrict__ m_p,  const float* __restrict__ v_p,
    const float* __restrict__ ab,   const int* __restrict__ idxs,
    _Float16* __restrict__ WkvF, _Float16* __restrict__ WqF,
    _Float16* __restrict__ WpF,
    float* __restrict__ kv_s, float* __restrict__ kv_sh,
    float* __restrict__ q_s,  float* __restrict__ q_sh,
    float* __restrict__ p_s,  float* __restrict__ p_sh,
    float* __restrict__ biasF)
{
  int i = blockIdx.x * 256 + threadIdx.x;
  if (i < 12288) {                       // WkvF: 24 tiles x 8 kc x 64 lanes
    int lane = i & 63, kc = (i >> 6) & 7, tile = i >> 9;
    const float* src = Wkv + (size_t)(tile * 16 + (lane & 15)) * Cn + kc * 32 + (lane >> 4) * 8;
    half8v hv;
#pragma unroll
    for (int j = 0; j < 8; ++j) hv[j] = (_Float16)src[j];
    *reinterpret_cast<half8v*>(WkvF + (size_t)i * 8) = hv;
    return;
  }
  i -= 12288;
  if (i < 4096) {                        // WqF: 8 tiles
    int lane = i & 63, kc = (i >> 6) & 7, tile = i >> 9;
    const float* src = Wq + (size_t)(tile * 16 + (lane & 15)) * Cn + kc * 32 + (lane >> 4) * 8;
    half8v hv;
#pragma unroll
    for (int j = 0; j < 8; ++j) hv[j] = (_Float16)src[j];
    *reinterpret_cast<half8v*>(WqF + (size_t)i * 8) = hv;
    return;
  }
  i -= 4096;
  if (i < 12288) {                       // WpF: 24 tiles
    int lane = i & 63, kc = (i >> 6) & 7, tile = i >> 9;
    const float* src = Wp + (size_t)(tile * 16 + (lane & 15)) * Cn + kc * 32 + (lane >> 4) * 8;
    half8v hv;
#pragma unroll
    for (int j = 0; j < 8; ++j) hv[j] = (_Float16)src[j];
    *reinterpret_cast<half8v*>(WpF + (size_t)i * 8) = hv;
    return;
  }
  i -= 12288;
  if (i < 26624) {                       // biasF: 8h x 4qt x 13nt x 64 lanes
    int lane = i & 63;
    int v = i >> 6;
    int nt = v % 13;  v /= 13;
    int qt = v & 3, h = v >> 2;
    int r = lane & 15, g = lane >> 4;
    int n = nt * 16 + r; if (n > 195) n = 195;
    float4v bv;
#pragma unroll
    for (int j = 0; j < 4; ++j) {
      int q = qt * 16 + g * 4 + j; if (q > 48) q = 48;
      bv[j] = ab[h * Nn + idxs[q * Nn + n]];
    }
    *reinterpret_cast<float4v*>(biasF + (size_t)i * 4) = bv;
    return;
  }
  i -= 26624;
  if (i < 896) {
    if (i < 384) {
      float s = g_kv[i] * rsqrtf(v_kv[i] + 1e-5f);
      kv_s[i] = s; kv_sh[i] = b_kv[i] - m_kv[i] * s;
    } else if (i < 512) {
      int j = i - 384;
      float s = g_q[j] * rsqrtf(v_q[j] + 1e-5f);
      q_s[j] = 0.25f * s; q_sh[j] = 0.25f * (b_q[j] - m_q[j] * s);
    } else {
      int j = i - 512;
      float s = g_p[j] * rsqrtf(v_p[j] + 1e-5f);
      p_s[j] = s; p_sh[j] = b_p[j] - m_p[j] * s;
    }
  }
}

// ------------------------------------------------------------- kv gemm ----
// grid (512, 4): batch b x ttile-chunk {0..3}->{[0,4),[4,7),[7,10),[10,13)}.
// 512 threads = 8 waves, wave = one head. x-tile staged once to LDS in frag
// order; W frags in registers. k in mfma(W,x) orientation (D lane = token,
// 4 channels) -> kkF packed; v in mfma(x,W) (D lane = vd, 4 tokens) -> vF.
__global__ __launch_bounds__(512) void kv_gemm_kernel(
    const float* __restrict__ x, const _Float16* __restrict__ WkvF,
    const float* __restrict__ kv_s, const float* __restrict__ kv_sh,
    _Float16* __restrict__ kkF, _Float16* __restrict__ vF)
{
  const int b = blockIdx.x;
  const int by = blockIdx.y;
  const int ts = (by == 0) ? 0 : (3 * by + 1);
  const int cnt = (by == 0) ? 4 : 3;
  const int tid = threadIdx.x, lane = tid & 63, wid = tid >> 6;
  const int cg = lane >> 4, ci = lane & 15;

  __shared__ _Float16 sxf[4 * 8 * 64 * 8];   // 32 KB, frag order [tl][kc][lane][8]

  // ---- stage x-tile (up to 64 tokens) as f16 fragments ------------------
#pragma unroll
  for (int r = 0; r < 4; ++r) {
    int c = r * 512 + tid;                   // 0..2047 16B-chunks
    int ln = c & 63, kc = (c >> 6) & 7, tl = c >> 9;
    int m = ln & 15, g = ln >> 4;
    int t = (ts + tl) * 16 + m;
    half8v hv;
    if (t < Nn) {
      const float* src = x + ((size_t)b * Nn + t) * Cn + kc * 32 + g * 8;
      float4v a0 = *reinterpret_cast<const float4v*>(src);
      float4v a1 = *reinterpret_cast<const float4v*>(src + 4);
      hv[0]=(_Float16)a0[0]; hv[1]=(_Float16)a0[1]; hv[2]=(_Float16)a0[2]; hv[3]=(_Float16)a0[3];
      hv[4]=(_Float16)a1[0]; hv[5]=(_Float16)a1[1]; hv[6]=(_Float16)a1[2]; hv[7]=(_Float16)a1[3];
    } else {
      hv = (half8v)(_Float16)0.f;
    }
    *reinterpret_cast<half8v*>(sxf + (size_t)c * 8) = hv;
  }
  __syncthreads();

  const int h = wid;
  // ---- W fragments (3 tiles x 8 kc) in registers ------------------------
  const _Float16* Wb = WkvF + (size_t)(3 * h) * 8 * 64 * 8;
  half8v wk[8], w0[8], w1[8];
#pragma unroll
  for (int kc = 0; kc < 8; ++kc) {
    wk[kc] = *reinterpret_cast<const half8v*>(Wb + (size_t)(kc * 64 + lane) * 8);
    w0[kc] = *reinterpret_cast<const half8v*>(Wb + (size_t)((8 + kc) * 64 + lane) * 8);
    w1[kc] = *reinterpret_cast<const half8v*>(Wb + (size_t)((16 + kc) * 64 + lane) * 8);
  }
  // ---- norm params ------------------------------------------------------
  float sk[4], shk[4];
#pragma unroll
  for (int j = 0; j < 4; ++j) {
    sk[j]  = kv_s [48 * h + cg * 4 + j];
    shk[j] = kv_sh[48 * h + cg * 4 + j];
  }
  const float sv0 = kv_s[48 * h + 16 + ci], shv0 = kv_sh[48 * h + 16 + ci];
  const float sv1 = kv_s[48 * h + 32 + ci], shv1 = kv_sh[48 * h + 32 + ci];

  const size_t bh = (size_t)b * 8 + h;
  for (int tl = 0; tl < cnt; ++tl) {
    half8v af[8];
#pragma unroll
    for (int kc = 0; kc < 8; ++kc)
      af[kc] = *reinterpret_cast<const half8v*>(sxf + (size_t)((tl * 8 + kc) * 64 + lane) * 8);
    const int t16 = ts + tl;
    float4v a0 = (float4v){0.f,0.f,0.f,0.f};
    float4v a1 = (float4v){0.f,0.f,0.f,0.f};
    float4v a2 = (float4v){0.f,0.f,0.f,0.f};
#pragma unroll
    for (int kc = 0; kc < 8; ++kc) {
      a0 = __builtin_amdgcn_mfma_f32_16x16x32_f16(wk[kc], af[kc], a0, 0, 0, 0);
      a1 = __builtin_amdgcn_mfma_f32_16x16x32_f16(af[kc], w0[kc], a1, 0, 0, 0);
      a2 = __builtin_amdgcn_mfma_f32_16x16x32_f16(af[kc], w1[kc], a2, 0, 0, 0);
    }
    half4v hk, h0, h1;
#pragma unroll
    for (int j = 0; j < 4; ++j) {
      hk[j] = (_Float16)(a0[j] * sk[j] + shk[j]);
      h0[j] = (_Float16)(a1[j] * sv0 + shv0);
      h1[j] = (_Float16)(a2[j] * sv1 + shv1);
    }
    *reinterpret_cast<half4v*>(kkF + ((bh * 13 + t16) * 64 + lane) * 4)           = hk;
    *reinterpret_cast<half4v*>(vF  + (((bh * 13 + t16) * 2 + 0) * 64 + lane) * 4) = h0;
    *reinterpret_cast<half4v*>(vF  + (((bh * 13 + t16) * 2 + 1) * 64 + lane) * 4) = h1;
  }
}

// -------------------------------------------------------------- q gemm ----
// grid (512, 4): batch x q-tile. 4 waves, wave = 2 heads. ori-2 (mfma(W,x))
// -> D lane = q-row, 4 channels -> qF packed for attn's A-fragment.
__global__ __launch_bounds__(256) void q_gemm_kernel(
    const float* __restrict__ x, const _Float16* __restrict__ WqF,
    const float* __restrict__ q_s, const float* __restrict__ q_sh,
    _Float16* __restrict__ qF)
{
  const int b = blockIdx.x, qt = blockIdx.y;
  const int tid = threadIdx.x, lane = tid & 63, wid = tid >> 6;
  const int cg = lane >> 4, mq = lane & 15;

  const int q = qt * 16 + mq;
  half8v af[8];
  if (q < NQn) {
    const int qi = q / 7, qj = q - qi * 7;
    const int tok = 28 * qi + 2 * qj;
    const float* src = x + ((size_t)b * Nn + tok) * Cn + cg * 8;
#pragma unroll
    for (int kc = 0; kc < 8; ++kc) {
      float4v a0 = *reinterpret_cast<const float4v*>(src + kc * 32);
      float4v a1 = *reinterpret_cast<const float4v*>(src + kc * 32 + 4);
      half8v t;
      t[0]=(_Float16)a0[0]; t[1]=(_Float16)a0[1]; t[2]=(_Float16)a0[2]; t[3]=(_Float16)a0[3];
      t[4]=(_Float16)a1[0]; t[5]=(_Float16)a1[1]; t[6]=(_Float16)a1[2]; t[7]=(_Float16)a1[3];
      af[kc] = t;
    }
  } else {
#pragma unroll
    for (int kc = 0; kc < 8; ++kc) af[kc] = (half8v)(_Float16)0.f;
  }

#pragma unroll
  for (int hh = 0; hh < 2; ++hh) {
    const int h = wid * 2 + hh;
    half8v wq[8];
#pragma unroll
    for (int kc = 0; kc < 8; ++kc)
      wq[kc] = *reinterpret_cast<const half8v*>(WqF + (size_t)((h * 8 + kc) * 64 + lane) * 8);
    float4v acc = (float4v){0.f,0.f,0.f,0.f};
#pragma unroll
    for (int kc = 0; kc < 8; ++kc)
      acc = __builtin_amdgcn_mfma_f32_16x16x32_f16(wq[kc], af[kc], acc, 0, 0, 0);
    half4v hq;
#pragma unroll
    for (int j = 0; j < 4; ++j) {
      int c = 16 * h + cg * 4 + j;
      hq[j] = (_Float16)(acc[j] * q_s[c] + q_sh[c]);
    }
    *reinterpret_cast<half4v*>(qF + ((((size_t)b * 8 + h) * 4 + qt) * 64 + lane) * 4) = hq;
  }
}

// ---------------------------------------------------------------- attn ----
// grid 4096 (b*8+h). All fragment loads coalesced 512B/1KB runs.
__global__ __launch_bounds__(256) void attn_kernel(
    const _Float16* __restrict__ kkF, const _Float16* __restrict__ vF,
    const _Float16* __restrict__ qF, const float* __restrict__ biasF,
    _Float16* __restrict__ oh)
{
  const int bh = blockIdx.x;
  const int b = bh >> 3, h = bh & 7;
  const int tid = threadIdx.x, lane = tid & 63, wid = tid >> 6;
  const int row_in = lane & 15, kgrp = lane >> 4;

  __shared__ _Float16 sP[4][16][212];

  // ---- QK^T + bias ------------------------------------------------------
  half4v aq = *reinterpret_cast<const half4v*>(
      qF + (((size_t)bh * 4 + wid) * 64 + lane) * 4);
  const _Float16* kb = kkF + (size_t)bh * 13 * 64 * 4;
  const float* bb = biasF + (size_t)(h * 4 + wid) * 13 * 64 * 4;

  float4v acc[13];
#pragma unroll
  for (int nt = 0; nt < 13; ++nt) {
    half4v bk = *reinterpret_cast<const half4v*>(kb + (nt * 64 + lane) * 4);
    float4v a = (float4v){0.f,0.f,0.f,0.f};
    a = __builtin_amdgcn_mfma_f32_16x16x16f16(aq, bk, a, 0, 0, 0);
    float4v bias = *reinterpret_cast<const float4v*>(bb + (size_t)(nt * 64 + lane) * 4);
    acc[nt] = a + bias;
  }

  // ---- register softmax -------------------------------------------------
  const bool tail_ok = (row_in < 4);
  float mx[4], sm[4];
#pragma unroll
  for (int i = 0; i < 4; ++i) mx[i] = -1e30f;
#pragma unroll
  for (int nt = 0; nt < 13; ++nt) {
    bool valid = (nt < 12) | tail_ok;
#pragma unroll
    for (int i = 0; i < 4; ++i)
      mx[i] = fmaxf(mx[i], valid ? acc[nt][i] : -1e30f);
  }
#pragma unroll
  for (int i = 0; i < 4; ++i) {
#pragma unroll
    for (int off = 8; off >= 1; off >>= 1)
      mx[i] = fmaxf(mx[i], __shfl_xor(mx[i], off, 64));
  }
#pragma unroll
  for (int i = 0; i < 4; ++i) sm[i] = 0.f;
#pragma unroll
  for (int nt = 0; nt < 13; ++nt) {
    bool valid = (nt < 12) | tail_ok;
#pragma unroll
    for (int i = 0; i < 4; ++i) {
      float e = valid ? __expf(acc[nt][i] - mx[i]) : 0.f;
      acc[nt][i] = e; sm[i] += e;
    }
  }
#pragma unroll
  for (int i = 0; i < 4; ++i) {
#pragma unroll
    for (int off = 8; off >= 1; off >>= 1)
      sm[i] += __shfl_xor(sm[i], off, 64);
  }
  float inv[4];
#pragma unroll
  for (int i = 0; i < 4; ++i) inv[i] = 1.f / sm[i];

  // ---- P -> per-wave LDS ------------------------------------------------
#pragma unroll
  for (int nt = 0; nt < 13; ++nt)
#pragma unroll
    for (int i = 0; i < 4; ++i)
      sP[wid][kgrp * 4 + i][nt * 16 + row_in] = (_Float16)(acc[nt][i] * inv[i]);

  // ---- O = P @ V --------------------------------------------------------
  const _Float16* vb = vF + (size_t)bh * 13 * 2 * 64 * 4;
  float4v o0 = (float4v){0.f,0.f,0.f,0.f};
  float4v o1 = (float4v){0.f,0.f,0.f,0.f};
#pragma unroll
  for (int kc = 0; kc < 13; ++kc) {
    half4v ap  = *reinterpret_cast<const half4v*>(&sP[wid][row_in][kc * 16 + kgrp * 4]);
    half4v bv0 = *reinterpret_cast<const half4v*>(vb + ((kc * 2 + 0) * 64 + lane) * 4);
    half4v bv1 = *reinterpret_cast<const half4v*>(vb + ((kc * 2 + 1) * 64 + lane) * 4);
    o0 = __builtin_amdgcn_mfma_f32_16x16x16f16(ap, bv0, o0, 0, 0, 0);
    o1 = __builtin_amdgcn_mfma_f32_16x16x16f16(ap, bv1, o1, 0, 0, 0);
  }
#pragma unroll
  for (int i = 0; i < 4; ++i) {
    int q = wid * 16 + kgrp * 4 + i;
    if (q < NQn) {
      size_t base = ((size_t)b * NQn + q) * 256 + h * 32 + row_in;
      float v0 = o0[i], v1 = o1[i];
      float hs0 = v0 * fminf(fmaxf(v0 + 3.f, 0.f), 6.f) * (1.f / 6.f);
      float hs1 = v1 * fminf(fmaxf(v1 + 3.f, 0.f), 6.f) * (1.f / 6.f);
      oh[base]      = (_Float16)hs0;
      oh[base + 16] = (_Float16)hs1;
    }
  }
}

// ---------------------------------------------------------------- proj ----
// grid (392, 3): 64 rows x 128 cols; A from oh, W frags coalesced from WpF.
__global__ __launch_bounds__(256) void proj_kernel(
    const _Float16* __restrict__ oh, const _Float16* __restrict__ WpF,
    const float* __restrict__ p_s, const float* __restrict__ p_sh,
    float* __restrict__ out)
{
  const int tid = threadIdx.x, lane = tid & 63, wid = tid >> 6;
  const int row_in = lane & 15, kgrp = lane >> 4;
  const size_t g_a = (size_t)blockIdx.x * 64 + wid * 16 + row_in;
  const int jt0 = blockIdx.y * 8;

  half8v af[8];
  const _Float16* arow = oh + g_a * 256 + kgrp * 8;
#pragma unroll
  for (int kc = 0; kc < 8; ++kc)
    af[kc] = *reinterpret_cast<const half8v*>(arow + kc * 32);

  const size_t r0 = (size_t)blockIdx.x * 64 + wid * 16 + kgrp * 4;
#pragma unroll
  for (int nt = 0; nt < 8; ++nt) {
    float4v acc = (float4v){0.f,0.f,0.f,0.f};
#pragma unroll
    for (int kc = 0; kc < 8; ++kc) {
      half8v bf = *reinterpret_cast<const half8v*>(
          WpF + (size_t)(((jt0 + nt) * 8 + kc) * 64 + lane) * 8);
      acc = __builtin_amdgcn_mfma_f32_16x16x32_f16(af[kc], bf, acc, 0, 0, 0);
    }
    int j = (jt0 + nt) * 16 + row_in;
    float s = p_s[j], sh = p_sh[j];
#pragma unroll
    for (int i = 0; i < 4; ++i)
      out[(r0 + i) * 384 + j] = acc[i] * s + sh;
  }
}

// -------------------------------------------------------------- launch ----
extern "C" void kernel_launch(void* const* d_in, const int* in_sizes, int n_in,
                              void* d_out, int out_size, void* d_ws, size_t ws_size,
                              hipStream_t stream) {
  const float* x    = (const float*)d_in[0];
  const float* Wkv  = (const float*)d_in[1];
  const float* g_kv = (const float*)d_in[2];
  const float* b_kv = (const float*)d_in[3];
  const float* m_kv = (const float*)d_in[4];
  const float* v_kv = (const float*)d_in[5];
  const float* Wq   = (const float*)d_in[6];
  const float* g_q  = (const float*)d_in[7];
  const float* b_q  = (const float*)d_in[8];
  const float* m_q  = (const float*)d_in[9];
  const float* v_q  = (const float*)d_in[10];
  const float* Wp   = (const float*)d_in[11];
  const float* g_p  = (const float*)d_in[12];
  const float* b_p  = (const float*)d_in[13];
  const float* m_p  = (const float*)d_in[14];
  const float* v_p  = (const float*)d_in[15];
  const float* ab   = (const float*)d_in[16];
  const int*   idxs = (const int*)d_in[17];
  float* out = (float*)d_out;

  // workspace carve (~104 MB, same extents as round 3)
  char* w = (char*)d_ws;
  _Float16* oh    = (_Float16*)(w);                     // 25088*256*2     = 12,845,056
  _Float16* kkF   = (_Float16*)(w + 12845056);          // 4096*13*64*4*2  = 27,262,976
  _Float16* vF    = (_Float16*)(w + 40108032);          // 4096*13*2*64*4*2= 54,525,952
  _Float16* qF    = (_Float16*)(w + 94633984);          // 4096*4*64*4*2   =  8,388,608
  _Float16* WkvF  = (_Float16*)(w + 103022592);         // 12288*8*2       =    196,608
  _Float16* WqF   = (_Float16*)(w + 103219200);         // 4096*8*2        =     65,536
  _Float16* WpF   = (_Float16*)(w + 103284736);         // 12288*8*2       =    196,608
  float*    biasF = (float*)   (w + 103481344);         // 26624*4*4       =    425,984
  float*    kv_s  = (float*)   (w + 103907328);
  float*    kv_sh = (float*)   (w + 103908864);
  float*    q_s   = (float*)   (w + 103910400);
  float*    q_sh  = (float*)   (w + 103910912);
  float*    p_s   = (float*)   (w + 103911424);
  float*    p_sh  = (float*)   (w + 103912960);

  prep_kernel<<<220, 256, 0, stream>>>(Wkv, Wq, Wp,
                                       g_kv, b_kv, m_kv, v_kv,
                                       g_q, b_q, m_q, v_q,
                                       g_p, b_p, m_p, v_p,
                                       ab, idxs,
                                       WkvF, WqF, WpF,
                                       kv_s, kv_sh, q_s, q_sh, p_s, p_sh, biasF);
  kv_gemm_kernel<<<dim3(Bn, 4), 512, 0, stream>>>(x, WkvF, kv_s, kv_sh, kkF, vF);
  q_gemm_kernel<<<dim3(Bn, 4), 256, 0, stream>>>(x, WqF, q_s, q_sh, qF);
  attn_kernel<<<Bn * Hn, 256, 0, stream>>>(kkF, vF, qF, biasF, oh);
  proj_kernel<<<dim3(392, 3), 256, 0, stream>>>(oh, WpF, p_s, p_sh, out);
}

// Round 5
// 282.689 us; speedup vs baseline: 1.7166x; 1.0360x over previous
//
#include <hip/hip_runtime.h>

// AttentionSubsample (LeViT) — round 5.
// Round-4 diagnosis: kv_gemm VGPR_Count=72 < 96 needed for hoisted W frags ->
// compiler re-loaded W per tile (1.57 GB L2 traffic). Fix: kc-outer loop (W
// loaded once per kc, 12 independent MFMA chains), launch_bounds(512,4).
// q_gemm merged into the same launch as blockIdx.y==4.

#define Bn   512
#define Nn   196
#define NQn  49
#define Cn   256
#define Hn   8

typedef float    float4v __attribute__((ext_vector_type(4)));
typedef _Float16 half8v  __attribute__((ext_vector_type(8)));
typedef _Float16 half4v  __attribute__((ext_vector_type(4)));

// ---------------------------------------------------------------- prep ----
// Packs weights/bias into fragment order; folds BN params.
//   WF[tile][kc][lane]  (16B/lane):  W[tile*16 + (lane&15)][kc*32 + (lane>>4)*8 .. +8]
//   biasF[h][qt][nt][lane] (float4): ab[h, idxs[qt*16+(lane>>4)*4+i, nt*16+(lane&15)]]
__global__ __launch_bounds__(256) void prep_kernel(
    const float* __restrict__ Wkv, const float* __restrict__ Wq,
    const float* __restrict__ Wp,
    const float* __restrict__ g_kv, const float* __restrict__ b_kv,
    const float* __restrict__ m_kv, const float* __restrict__ v_kv,
    const float* __restrict__ g_q,  const float* __restrict__ b_q,
    const float* __restrict__ m_q,  const float* __restrict__ v_q,
    const float* __restrict__ g_p,  const float* __restrict__ b_p,
    const float* __restrict__ m_p,  const float* __restrict__ v_p,
    const float* __restrict__ ab,   const int* __restrict__ idxs,
    _Float16* __restrict__ WkvF, _Float16* __restrict__ WqF,
    _Float16* __restrict__ WpF,
    float* __restrict__ kv_s, float* __restrict__ kv_sh,
    float* __restrict__ q_s,  float* __restrict__ q_sh,
    float* __restrict__ p_s,  float* __restrict__ p_sh,
    float* __restrict__ biasF)
{
  int i = blockIdx.x * 256 + threadIdx.x;
  if (i < 12288) {                       // WkvF: 24 tiles x 8 kc x 64 lanes
    int lane = i & 63, kc = (i >> 6) & 7, tile = i >> 9;
    const float* src = Wkv + (size_t)(tile * 16 + (lane & 15)) * Cn + kc * 32 + (lane >> 4) * 8;
    half8v hv;
#pragma unroll
    for (int j = 0; j < 8; ++j) hv[j] = (_Float16)src[j];
    *reinterpret_cast<half8v*>(WkvF + (size_t)i * 8) = hv;
    return;
  }
  i -= 12288;
  if (i < 4096) {                        // WqF: 8 tiles
    int lane = i & 63, kc = (i >> 6) & 7, tile = i >> 9;
    const float* src = Wq + (size_t)(tile * 16 + (lane & 15)) * Cn + kc * 32 + (lane >> 4) * 8;
    half8v hv;
#pragma unroll
    for (int j = 0; j < 8; ++j) hv[j] = (_Float16)src[j];
    *reinterpret_cast<half8v*>(WqF + (size_t)i * 8) = hv;
    return;
  }
  i -= 4096;
  if (i < 12288) {                       // WpF: 24 tiles
    int lane = i & 63, kc = (i >> 6) & 7, tile = i >> 9;
    const float* src = Wp + (size_t)(tile * 16 + (lane & 15)) * Cn + kc * 32 + (lane >> 4) * 8;
    half8v hv;
#pragma unroll
    for (int j = 0; j < 8; ++j) hv[j] = (_Float16)src[j];
    *reinterpret_cast<half8v*>(WpF + (size_t)i * 8) = hv;
    return;
  }
  i -= 12288;
  if (i < 26624) {                       // biasF: 8h x 4qt x 13nt x 64 lanes
    int lane = i & 63;
    int v = i >> 6;
    int nt = v % 13;  v /= 13;
    int qt = v & 3, h = v >> 2;
    int r = lane & 15, g = lane >> 4;
    int n = nt * 16 + r; if (n > 195) n = 195;
    float4v bv;
#pragma unroll
    for (int j = 0; j < 4; ++j) {
      int q = qt * 16 + g * 4 + j; if (q > 48) q = 48;
      bv[j] = ab[h * Nn + idxs[q * Nn + n]];
    }
    *reinterpret_cast<float4v*>(biasF + (size_t)i * 4) = bv;
    return;
  }
  i -= 26624;
  if (i < 896) {
    if (i < 384) {
      float s = g_kv[i] * rsqrtf(v_kv[i] + 1e-5f);
      kv_s[i] = s; kv_sh[i] = b_kv[i] - m_kv[i] * s;
    } else if (i < 512) {
      int j = i - 384;
      float s = g_q[j] * rsqrtf(v_q[j] + 1e-5f);
      q_s[j] = 0.25f * s; q_sh[j] = 0.25f * (b_q[j] - m_q[j] * s);
    } else {
      int j = i - 512;
      float s = g_p[j] * rsqrtf(v_p[j] + 1e-5f);
      p_s[j] = s; p_sh[j] = b_p[j] - m_p[j] * s;
    }
  }
}

// ----------------------------------------------------------- kv+q gemm ----
// grid (512, 5), 512 threads = 8 waves (wave = head).
//  by<4 : kv path — ttile chunk {[0,4),[4,7),[7,10),[10,13)}. x-tile staged
//         once (frag order), kc-outer loop: 3 W frags live at a time, 12
//         independent MFMA chains. k in mfma(W,x), v in mfma(x,W).
//  by==4: q path — 49 strided rows staged in frag order, mfma(Wq,x).
__global__ __launch_bounds__(512, 4) void kvq_gemm_kernel(
    const float* __restrict__ x,
    const _Float16* __restrict__ WkvF, const _Float16* __restrict__ WqF,
    const float* __restrict__ kv_s, const float* __restrict__ kv_sh,
    const float* __restrict__ q_s,  const float* __restrict__ q_sh,
    _Float16* __restrict__ kkF, _Float16* __restrict__ vF,
    _Float16* __restrict__ qF)
{
  const int b = blockIdx.x, by = blockIdx.y;
  const int tid = threadIdx.x, lane = tid & 63, wid = tid >> 6;
  const int cg = lane >> 4, ci = lane & 15;

  __shared__ _Float16 sxf[4 * 8 * 64 * 8];   // 32 KB, frag order [tl][kc][lane][8]

  if (by < 4) {
    const int ts = (by == 0) ? 0 : (3 * by + 1);
    const int cnt = (by == 0) ? 4 : 3;

    // ---- stage x-tile as f16 fragments (coalesced 128B-per-row runs) ----
#pragma unroll
    for (int r = 0; r < 4; ++r) {
      int c = r * 512 + tid;                 // 0..2047 16B chunks
      int ln = c & 63, kc = (c >> 6) & 7, tl = c >> 9;
      int t = (ts + tl) * 16 + (ln & 15);
      half8v hv;
      if (t < Nn) {
        const float* src = x + ((size_t)b * Nn + t) * Cn + kc * 32 + (ln >> 4) * 8;
        float4v a0 = *reinterpret_cast<const float4v*>(src);
        float4v a1 = *reinterpret_cast<const float4v*>(src + 4);
        hv[0]=(_Float16)a0[0]; hv[1]=(_Float16)a0[1]; hv[2]=(_Float16)a0[2]; hv[3]=(_Float16)a0[3];
        hv[4]=(_Float16)a1[0]; hv[5]=(_Float16)a1[1]; hv[6]=(_Float16)a1[2]; hv[7]=(_Float16)a1[3];
      } else {
        hv = (half8v)(_Float16)0.f;
      }
      *reinterpret_cast<half8v*>(sxf + (size_t)c * 8) = hv;
    }
    __syncthreads();

    const int h = wid;
    const _Float16* Wb = WkvF + (size_t)(3 * h) * 8 * 64 * 8;

    float4v acK[4], acV0[4], acV1[4];
#pragma unroll
    for (int tl = 0; tl < 4; ++tl) {
      acK[tl]  = (float4v){0.f,0.f,0.f,0.f};
      acV0[tl] = (float4v){0.f,0.f,0.f,0.f};
      acV1[tl] = (float4v){0.f,0.f,0.f,0.f};
    }
#pragma unroll
    for (int kc = 0; kc < 8; ++kc) {
      half8v wk = *reinterpret_cast<const half8v*>(Wb + (size_t)(kc * 64 + lane) * 8);
      half8v w0 = *reinterpret_cast<const half8v*>(Wb + (size_t)((8 + kc) * 64 + lane) * 8);
      half8v w1 = *reinterpret_cast<const half8v*>(Wb + (size_t)((16 + kc) * 64 + lane) * 8);
#pragma unroll
      for (int tl = 0; tl < 4; ++tl) {
        half8v a = *reinterpret_cast<const half8v*>(sxf + (size_t)((tl * 8 + kc) * 64 + lane) * 8);
        acK[tl]  = __builtin_amdgcn_mfma_f32_16x16x32_f16(wk, a, acK[tl], 0, 0, 0);
        acV0[tl] = __builtin_amdgcn_mfma_f32_16x16x32_f16(a, w0, acV0[tl], 0, 0, 0);
        acV1[tl] = __builtin_amdgcn_mfma_f32_16x16x32_f16(a, w1, acV1[tl], 0, 0, 0);
      }
    }

    float sk0[4], shk0[4];
#pragma unroll
    for (int j = 0; j < 4; ++j) {
      sk0[j]  = kv_s [48 * h + cg * 4 + j];
      shk0[j] = kv_sh[48 * h + cg * 4 + j];
    }
    const float sv0 = kv_s[48 * h + 16 + ci], shv0 = kv_sh[48 * h + 16 + ci];
    const float sv1 = kv_s[48 * h + 32 + ci], shv1 = kv_sh[48 * h + 32 + ci];
    const size_t bh = (size_t)b * 8 + h;

#pragma unroll
    for (int tl = 0; tl < 4; ++tl) {
      if (tl < cnt) {
        const int t16 = ts + tl;
        half4v hk, h0, h1;
#pragma unroll
        for (int j = 0; j < 4; ++j) {
          hk[j] = (_Float16)(acK[tl][j]  * sk0[j] + shk0[j]);
          h0[j] = (_Float16)(acV0[tl][j] * sv0 + shv0);
          h1[j] = (_Float16)(acV1[tl][j] * sv1 + shv1);
        }
        *reinterpret_cast<half4v*>(kkF + ((bh * 13 + t16) * 64 + lane) * 4)           = hk;
        *reinterpret_cast<half4v*>(vF  + (((bh * 13 + t16) * 2 + 0) * 64 + lane) * 4) = h0;
        *reinterpret_cast<half4v*>(vF  + (((bh * 13 + t16) * 2 + 1) * 64 + lane) * 4) = h1;
      }
    }
  } else {
    // ---- q path: stage 49 strided rows in frag order (qt tiles) ---------
#pragma unroll
    for (int r = 0; r < 4; ++r) {
      int c = r * 512 + tid;
      int ln = c & 63, kc = (c >> 6) & 7, tl = c >> 9;
      int qi_ = tl * 16 + (ln & 15);
      half8v hv;
      if (qi_ < NQn) {
        int qr = qi_ / 7, qc2 = qi_ - qr * 7;
        int t = 28 * qr + 2 * qc2;
        const float* src = x + ((size_t)b * Nn + t) * Cn + kc * 32 + (ln >> 4) * 8;
        float4v a0 = *reinterpret_cast<const float4v*>(src);
        float4v a1 = *reinterpret_cast<const float4v*>(src + 4);
        hv[0]=(_Float16)a0[0]; hv[1]=(_Float16)a0[1]; hv[2]=(_Float16)a0[2]; hv[3]=(_Float16)a0[3];
        hv[4]=(_Float16)a1[0]; hv[5]=(_Float16)a1[1]; hv[6]=(_Float16)a1[2]; hv[7]=(_Float16)a1[3];
      } else {
        hv = (half8v)(_Float16)0.f;
      }
      *reinterpret_cast<half8v*>(sxf + (size_t)c * 8) = hv;
    }
    __syncthreads();

    const int h = wid;
    float4v acQ[4];
#pragma unroll
    for (int tl = 0; tl < 4; ++tl) acQ[tl] = (float4v){0.f,0.f,0.f,0.f};
#pragma unroll
    for (int kc = 0; kc < 8; ++kc) {
      half8v wq = *reinterpret_cast<const half8v*>(WqF + (size_t)((h * 8 + kc) * 64 + lane) * 8);
#pragma unroll
      for (int tl = 0; tl < 4; ++tl) {
        half8v a = *reinterpret_cast<const half8v*>(sxf + (size_t)((tl * 8 + kc) * 64 + lane) * 8);
        acQ[tl] = __builtin_amdgcn_mfma_f32_16x16x32_f16(wq, a, acQ[tl], 0, 0, 0);
      }
    }
    float sq_[4], shq_[4];
#pragma unroll
    for (int j = 0; j < 4; ++j) {
      int c = 16 * h + cg * 4 + j;
      sq_[j] = q_s[c]; shq_[j] = q_sh[c];
    }
#pragma unroll
    for (int tl = 0; tl < 4; ++tl) {
      half4v hq;
#pragma unroll
      for (int j = 0; j < 4; ++j)
        hq[j] = (_Float16)(acQ[tl][j] * sq_[j] + shq_[j]);
      *reinterpret_cast<half4v*>(qF + ((((size_t)b * 8 + h) * 4 + tl) * 64 + lane) * 4) = hq;
    }
  }
}

// ---------------------------------------------------------------- attn ----
// grid 4096 (b*8+h). All fragment loads coalesced 512B/1KB runs.
__global__ __launch_bounds__(256) void attn_kernel(
    const _Float16* __restrict__ kkF, const _Float16* __restrict__ vF,
    const _Float16* __restrict__ qF, const float* __restrict__ biasF,
    _Float16* __restrict__ oh)
{
  const int bh = blockIdx.x;
  const int b = bh >> 3, h = bh & 7;
  const int tid = threadIdx.x, lane = tid & 63, wid = tid >> 6;
  const int row_in = lane & 15, kgrp = lane >> 4;

  __shared__ _Float16 sP[4][16][212];

  // ---- QK^T + bias ------------------------------------------------------
  half4v aq = *reinterpret_cast<const half4v*>(
      qF + (((size_t)bh * 4 + wid) * 64 + lane) * 4);
  const _Float16* kb = kkF + (size_t)bh * 13 * 64 * 4;
  const float* bb = biasF + (size_t)(h * 4 + wid) * 13 * 64 * 4;

  float4v acc[13];
#pragma unroll
  for (int nt = 0; nt < 13; ++nt) {
    half4v bk = *reinterpret_cast<const half4v*>(kb + (nt * 64 + lane) * 4);
    float4v a = (float4v){0.f,0.f,0.f,0.f};
    a = __builtin_amdgcn_mfma_f32_16x16x16f16(aq, bk, a, 0, 0, 0);
    float4v bias = *reinterpret_cast<const float4v*>(bb + (size_t)(nt * 64 + lane) * 4);
    acc[nt] = a + bias;
  }

  // ---- register softmax -------------------------------------------------
  const bool tail_ok = (row_in < 4);
  float mx[4], sm[4];
#pragma unroll
  for (int i = 0; i < 4; ++i) mx[i] = -1e30f;
#pragma unroll
  for (int nt = 0; nt < 13; ++nt) {
    bool valid = (nt < 12) | tail_ok;
#pragma unroll
    for (int i = 0; i < 4; ++i)
      mx[i] = fmaxf(mx[i], valid ? acc[nt][i] : -1e30f);
  }
#pragma unroll
  for (int i = 0; i < 4; ++i) {
#pragma unroll
    for (int off = 8; off >= 1; off >>= 1)
      mx[i] = fmaxf(mx[i], __shfl_xor(mx[i], off, 64));
  }
#pragma unroll
  for (int i = 0; i < 4; ++i) sm[i] = 0.f;
#pragma unroll
  for (int nt = 0; nt < 13; ++nt) {
    bool valid = (nt < 12) | tail_ok;
#pragma unroll
    for (int i = 0; i < 4; ++i) {
      float e = valid ? __expf(acc[nt][i] - mx[i]) : 0.f;
      acc[nt][i] = e; sm[i] += e;
    }
  }
#pragma unroll
  for (int i = 0; i < 4; ++i) {
#pragma unroll
    for (int off = 8; off >= 1; off >>= 1)
      sm[i] += __shfl_xor(sm[i], off, 64);
  }
  float inv[4];
#pragma unroll
  for (int i = 0; i < 4; ++i) inv[i] = 1.f / sm[i];

  // ---- P -> per-wave LDS ------------------------------------------------
#pragma unroll
  for (int nt = 0; nt < 13; ++nt)
#pragma unroll
    for (int i = 0; i < 4; ++i)
      sP[wid][kgrp * 4 + i][nt * 16 + row_in] = (_Float16)(acc[nt][i] * inv[i]);

  // ---- O = P @ V --------------------------------------------------------
  const _Float16* vb = vF + (size_t)bh * 13 * 2 * 64 * 4;
  float4v o0 = (float4v){0.f,0.f,0.f,0.f};
  float4v o1 = (float4v){0.f,0.f,0.f,0.f};
#pragma unroll
  for (int kc = 0; kc < 13; ++kc) {
    half4v ap  = *reinterpret_cast<const half4v*>(&sP[wid][row_in][kc * 16 + kgrp * 4]);
    half4v bv0 = *reinterpret_cast<const half4v*>(vb + ((kc * 2 + 0) * 64 + lane) * 4);
    half4v bv1 = *reinterpret_cast<const half4v*>(vb + ((kc * 2 + 1) * 64 + lane) * 4);
    o0 = __builtin_amdgcn_mfma_f32_16x16x16f16(ap, bv0, o0, 0, 0, 0);
    o1 = __builtin_amdgcn_mfma_f32_16x16x16f16(ap, bv1, o1, 0, 0, 0);
  }
#pragma unroll
  for (int i = 0; i < 4; ++i) {
    int q = wid * 16 + kgrp * 4 + i;
    if (q < NQn) {
      size_t base = ((size_t)b * NQn + q) * 256 + h * 32 + row_in;
      float v0 = o0[i], v1 = o1[i];
      float hs0 = v0 * fminf(fmaxf(v0 + 3.f, 0.f), 6.f) * (1.f / 6.f);
      float hs1 = v1 * fminf(fmaxf(v1 + 3.f, 0.f), 6.f) * (1.f / 6.f);
      oh[base]      = (_Float16)hs0;
      oh[base + 16] = (_Float16)hs1;
    }
  }
}

// ---------------------------------------------------------------- proj ----
// grid (392, 3): 64 rows x 128 cols; A from oh, W frags coalesced from WpF.
__global__ __launch_bounds__(256) void proj_kernel(
    const _Float16* __restrict__ oh, const _Float16* __restrict__ WpF,
    const float* __restrict__ p_s, const float* __restrict__ p_sh,
    float* __restrict__ out)
{
  const int tid = threadIdx.x, lane = tid & 63, wid = tid >> 6;
  const int row_in = lane & 15, kgrp = lane >> 4;
  const size_t g_a = (size_t)blockIdx.x * 64 + wid * 16 + row_in;
  const int jt0 = blockIdx.y * 8;

  half8v af[8];
  const _Float16* arow = oh + g_a * 256 + kgrp * 8;
#pragma unroll
  for (int kc = 0; kc < 8; ++kc)
    af[kc] = *reinterpret_cast<const half8v*>(arow + kc * 32);

  const size_t r0 = (size_t)blockIdx.x * 64 + wid * 16 + kgrp * 4;
#pragma unroll
  for (int nt = 0; nt < 8; ++nt) {
    float4v acc = (float4v){0.f,0.f,0.f,0.f};
#pragma unroll
    for (int kc = 0; kc < 8; ++kc) {
      half8v bf = *reinterpret_cast<const half8v*>(
          WpF + (size_t)(((jt0 + nt) * 8 + kc) * 64 + lane) * 8);
      acc = __builtin_amdgcn_mfma_f32_16x16x32_f16(af[kc], bf, acc, 0, 0, 0);
    }
    int j = (jt0 + nt) * 16 + row_in;
    float s = p_s[j], sh = p_sh[j];
#pragma unroll
    for (int i = 0; i < 4; ++i)
      out[(r0 + i) * 384 + j] = acc[i] * s + sh;
  }
}

// -------------------------------------------------------------- launch ----
extern "C" void kernel_launch(void* const* d_in, const int* in_sizes, int n_in,
                              void* d_out, int out_size, void* d_ws, size_t ws_size,
                              hipStream_t stream) {
  const float* x    = (const float*)d_in[0];
  const float* Wkv  = (const float*)d_in[1];
  const float* g_kv = (const float*)d_in[2];
  const float* b_kv = (const float*)d_in[3];
  const float* m_kv = (const float*)d_in[4];
  const float* v_kv = (const float*)d_in[5];
  const float* Wq   = (const float*)d_in[6];
  const float* g_q  = (const float*)d_in[7];
  const float* b_q  = (const float*)d_in[8];
  const float* m_q  = (const float*)d_in[9];
  const float* v_q  = (const float*)d_in[10];
  const float* Wp   = (const float*)d_in[11];
  const float* g_p  = (const float*)d_in[12];
  const float* b_p  = (const float*)d_in[13];
  const float* m_p  = (const float*)d_in[14];
  const float* v_p  = (const float*)d_in[15];
  const float* ab   = (const float*)d_in[16];
  const int*   idxs = (const int*)d_in[17];
  float* out = (float*)d_out;

  // workspace carve (~104 MB)
  char* w = (char*)d_ws;
  _Float16* oh    = (_Float16*)(w);                     // 25088*256*2     = 12,845,056
  _Float16* kkF   = (_Float16*)(w + 12845056);          // 4096*13*64*4*2  = 27,262,976
  _Float16* vF    = (_Float16*)(w + 40108032);          // 4096*13*2*64*4*2= 54,525,952
  _Float16* qF    = (_Float16*)(w + 94633984);          // 4096*4*64*4*2   =  8,388,608
  _Float16* WkvF  = (_Float16*)(w + 103022592);         // 12288*8*2       =    196,608
  _Float16* WqF   = (_Float16*)(w + 103219200);         // 4096*8*2        =     65,536
  _Float16* WpF   = (_Float16*)(w + 103284736);         // 12288*8*2       =    196,608
  float*    biasF = (float*)   (w + 103481344);         // 26624*4*4       =    425,984
  float*    kv_s  = (float*)   (w + 103907328);
  float*    kv_sh = (float*)   (w + 103908864);
  float*    q_s   = (float*)   (w + 103910400);
  float*    q_sh  = (float*)   (w + 103910912);
  float*    p_s   = (float*)   (w + 103911424);
  float*    p_sh  = (float*)   (w + 103912960);

  prep_kernel<<<220, 256, 0, stream>>>(Wkv, Wq, Wp,
                                       g_kv, b_kv, m_kv, v_kv,
                                       g_q, b_q, m_q, v_q,
                                       g_p, b_p, m_p, v_p,
                                       ab, idxs,
                                       WkvF, WqF, WpF,
                                       kv_s, kv_sh, q_s, q_sh, p_s, p_sh, biasF);
  kvq_gemm_kernel<<<dim3(Bn, 5), 512, 0, stream>>>(x, WkvF, WqF,
                                                   kv_s, kv_sh, q_s, q_sh,
                                                   kkF, vF, qF);
  attn_kernel<<<Bn * Hn, 256, 0, stream>>>(kkF, vF, qF, biasF, oh);
  proj_kernel<<<dim3(392, 3), 256, 0, stream>>>(oh, WpF, p_s, p_sh, out);
}